// Round 2
// baseline (287.085 us; speedup 1.0000x reference)
//
#include <hip/hip_runtime.h>

// PenalizedMSELoss: out = mean(w * (x - t)^2), w = 3.0 if (4.5 < x < 5.5 && t != 5) else 1.0
// x: float32[N], t: int32[N], out: float32[1].
// Memory-bound: 8 B/elem logical -> 268 MB -> ~43 us floor at 6.3 TB/s.
// R1: 105 us kernel @ 2.55 TB/s logical — MLP-bound (2 loads/iter then vmcnt(0)).
// R2: batch 4 strided chunks/iter -> 8 independent 16B loads in flight per wave.

#define LABEL_I   5
#define LOWER_F   4.5f
#define UPPER_F   5.5f
#define PENALTY_F 3.0f

__device__ __forceinline__ float term(float x, int t) {
    float d = x - (float)t;
    float w = (x > LOWER_F && x < UPPER_F && t != LABEL_I) ? PENALTY_F : 1.0f;
    return w * d * d;
}

__device__ __forceinline__ float term4(float4 xv, int4 tv) {
    return term(xv.x, tv.x) + term(xv.y, tv.y) + term(xv.z, tv.z) + term(xv.w, tv.w);
}

__global__ __launch_bounds__(256) void penal_mse_kernel(
        const float4* __restrict__ x4,
        const int4*  __restrict__ t4,
        float* __restrict__ out,
        int n4, float inv_n, int n_tail_start, int n_total,
        const float* __restrict__ x_scalar,
        const int*  __restrict__ t_scalar) {
    int tid    = blockIdx.x * blockDim.x + threadIdx.x;
    int stride = gridDim.x * blockDim.x;

    float s0 = 0.0f, s1 = 0.0f, s2 = 0.0f, s3 = 0.0f;

    // Main loop: 4 strided float4+int4 chunks per iteration. All 8 loads are
    // issued before any use -> 8 KB/wave outstanding instead of 2 KB.
    int i = tid;
    for (; i + 3 * stride < n4; i += 4 * stride) {
        float4 a0 = x4[i];
        float4 a1 = x4[i + stride];
        float4 a2 = x4[i + 2 * stride];
        float4 a3 = x4[i + 3 * stride];
        int4   b0 = t4[i];
        int4   b1 = t4[i + stride];
        int4   b2 = t4[i + 2 * stride];
        int4   b3 = t4[i + 3 * stride];
        s0 += term4(a0, b0);
        s1 += term4(a1, b1);
        s2 += term4(a2, b2);
        s3 += term4(a3, b3);
    }
    // Remainder float4 chunks.
    for (; i < n4; i += stride)
        s0 += term4(x4[i], t4[i]);

    float sum = (s0 + s1) + (s2 + s3);

    // Scalar tail (N % 4 != 0) — not taken for N = 33554432.
    for (int j = n_tail_start + tid; j < n_total; j += stride)
        sum += term(x_scalar[j], t_scalar[j]);

    // Wave-64 shuffle reduction.
    #pragma unroll
    for (int off = 32; off > 0; off >>= 1)
        sum += __shfl_down(sum, off, 64);

    __shared__ float wsum[4];  // 256 threads / 64 lanes
    int lane = threadIdx.x & 63;
    int wave = threadIdx.x >> 6;
    if (lane == 0) wsum[wave] = sum;
    __syncthreads();

    if (threadIdx.x == 0) {
        float bsum = (wsum[0] + wsum[1]) + (wsum[2] + wsum[3]);
        atomicAdd(out, bsum * inv_n);
    }
}

extern "C" void kernel_launch(void* const* d_in, const int* in_sizes, int n_in,
                              void* d_out, int out_size, void* d_ws, size_t ws_size,
                              hipStream_t stream) {
    const float* x = (const float*)d_in[0];
    const int*   t = (const int*)d_in[1];
    float* out = (float*)d_out;

    int n  = in_sizes[0];
    int n4 = n >> 2;           // float4 groups
    int n_tail_start = n4 << 2;
    float inv_n = 1.0f / (float)n;

    // d_out is poisoned to 0xAA before every call — zero it (async, capture-safe).
    hipMemsetAsync(d_out, 0, sizeof(float), stream);

    const int block = 256;
    int grid = 2048;  // 8 blocks/CU * 256 CUs = exactly one full residency
    if (grid > (n4 + block - 1) / block) grid = (n4 + block - 1) / block;
    if (grid < 1) grid = 1;

    penal_mse_kernel<<<grid, block, 0, stream>>>(
        (const float4*)x, (const int4*)t, out,
        n4, inv_n, n_tail_start, n, x, t);
}

// Round 3
// 273.515 us; speedup vs baseline: 1.0496x; 1.0496x over previous
//
#include <hip/hip_runtime.h>

// PenalizedMSELoss: out = mean(w * (x - t)^2), w = 3.0 if (4.5 < x < 5.5 && t != 5) else 1.0
// x: float32[N], t: int32[N], out: float32[1].
// Roofline: 268 MB logical read (~134 MB HBM + ~134 MB L3-warm) -> ~25-43 us floor.
// R1: 105 us @ 2.55 TB/s — latency-bound, 12 VGPR => 1-2 loads in flight.
// R2: 115 us — FAILED: compiler compacted to 32 VGPR, re-serialized the 8 loads.
// R3: sched_barrier(0) pins 8 loads (8 KB/wave) before the math; two-stage
//     reduction via d_ws kills 2048 same-address atomics.

#define LABEL_I   5
#define LOWER_F   4.5f
#define UPPER_F   5.5f
#define PENALTY_F 3.0f

__device__ __forceinline__ float term(float x, int t) {
    float d = x - (float)t;
    float w = (x > LOWER_F && x < UPPER_F && t != LABEL_I) ? PENALTY_F : 1.0f;
    return w * d * d;
}

__device__ __forceinline__ float term4(float4 xv, int4 tv) {
    return term(xv.x, tv.x) + term(xv.y, tv.y) + term(xv.z, tv.z) + term(xv.w, tv.w);
}

// Tile = 256 threads * K(4) float4-pairs = 1024 float4 from each array (16+16 KB).
#define TPB 1024

__global__ __launch_bounds__(256) void penal_mse_stage1(
        const float4* __restrict__ x4,
        const int4*  __restrict__ t4,
        float* __restrict__ partials,
        int n4, int tiles, int n_tail_start, int n_total,
        const float* __restrict__ x_scalar,
        const int*  __restrict__ t_scalar) {
    float s0 = 0.0f, s1 = 0.0f, s2 = 0.0f, s3 = 0.0f;

    // Grid-stride over contiguous tiles. Per iteration: 8 independent 16 B
    // loads issued back-to-back (coalesced 4 KB per load instr per block),
    // then a scheduling fence so the compiler CANNOT sink loads into the
    // math (R2 showed it re-serializes to save VGPRs otherwise).
    for (int tile = blockIdx.x; tile < tiles; tile += gridDim.x) {
        int base = tile * TPB + threadIdx.x;
        float4 a0 = x4[base];
        float4 a1 = x4[base + 256];
        float4 a2 = x4[base + 512];
        float4 a3 = x4[base + 768];
        int4   b0 = t4[base];
        int4   b1 = t4[base + 256];
        int4   b2 = t4[base + 512];
        int4   b3 = t4[base + 768];
        __builtin_amdgcn_sched_barrier(0);  // keep all 8 loads in flight
        s0 += term4(a0, b0);
        s1 += term4(a1, b1);
        s2 += term4(a2, b2);
        s3 += term4(a3, b3);
    }

    float sum = (s0 + s1) + (s2 + s3);

    // Leftover float4 groups beyond full tiles (empty for N = 2^25).
    for (int i = tiles * TPB + blockIdx.x * blockDim.x + threadIdx.x;
         i < n4; i += gridDim.x * blockDim.x)
        sum += term4(x4[i], t4[i]);

    // Scalar tail (N % 4 != 0) — empty for N = 2^25.
    for (int j = n_tail_start + blockIdx.x * blockDim.x + threadIdx.x;
         j < n_total; j += gridDim.x * blockDim.x)
        sum += term(x_scalar[j], t_scalar[j]);

    // Wave-64 shuffle reduction, then per-block partial to workspace.
    #pragma unroll
    for (int off = 32; off > 0; off >>= 1)
        sum += __shfl_down(sum, off, 64);

    __shared__ float wsum[4];
    int lane = threadIdx.x & 63;
    int wave = threadIdx.x >> 6;
    if (lane == 0) wsum[wave] = sum;
    __syncthreads();

    if (threadIdx.x == 0)
        partials[blockIdx.x] = (wsum[0] + wsum[1]) + (wsum[2] + wsum[3]);
}

__global__ __launch_bounds__(256) void penal_mse_stage2(
        const float* __restrict__ partials, int nparts,
        float* __restrict__ out, float inv_n) {
    float sum = 0.0f;
    for (int i = threadIdx.x; i < nparts; i += 256)
        sum += partials[i];

    #pragma unroll
    for (int off = 32; off > 0; off >>= 1)
        sum += __shfl_down(sum, off, 64);

    __shared__ float wsum[4];
    int lane = threadIdx.x & 63;
    int wave = threadIdx.x >> 6;
    if (lane == 0) wsum[wave] = sum;
    __syncthreads();

    if (threadIdx.x == 0)
        out[0] = ((wsum[0] + wsum[1]) + (wsum[2] + wsum[3])) * inv_n;
}

extern "C" void kernel_launch(void* const* d_in, const int* in_sizes, int n_in,
                              void* d_out, int out_size, void* d_ws, size_t ws_size,
                              hipStream_t stream) {
    const float* x = (const float*)d_in[0];
    const int*   t = (const int*)d_in[1];
    float* out = (float*)d_out;
    float* partials = (float*)d_ws;

    int n  = in_sizes[0];
    int n4 = n >> 2;              // float4 groups
    int n_tail_start = n4 << 2;
    int tiles = n4 / TPB;         // full tiles of 1024 float4-pairs
    float inv_n = 1.0f / (float)n;

    const int block = 256;
    const int grid = 2048;        // 8 blocks/CU; 4 tiles per block at N = 2^25

    penal_mse_stage1<<<grid, block, 0, stream>>>(
        (const float4*)x, (const int4*)t, partials,
        n4, tiles, n_tail_start, n, x, t);

    penal_mse_stage2<<<1, block, 0, stream>>>(partials, grid, out, inv_n);
}

// Round 4
// 249.977 us; speedup vs baseline: 1.1484x; 1.0942x over previous
//
#include <hip/hip_runtime.h>

// PenalizedMSELoss: out = mean(w * (x - t)^2), w = 3.0 if (4.5 < x < 5.5 && t != 5) else 1.0
// x: float32[N], t: int32[N], out: float32[1].
// 268 MB single-use read. Working set == 256 MiB == L3 size; harness restore
// keeps it L3-warm (R3: FETCH ~66 KB yet dur unchanged vs HBM-heavy R1).
// R1: 105 us, 12 VGPR (MLP~2).  R2: 115 us FAILED (compacted to 32 VGPR).
// R3: 99 us, 28 VGPR (MLP~4) — dur invariant to L3-hit fraction => read-path
//     limit ~2.7 TB/s suspected.
// R4: asm-pin all 8 loads live (reg-alloc can't undo), nontemporal (nt) loads,
//     interleaved x/t issue order for partial-vmcnt release.

#define LABEL_I   5
#define LOWER_F   4.5f
#define UPPER_F   5.5f
#define PENALTY_F 3.0f

typedef float vf4 __attribute__((ext_vector_type(4)));
typedef int   vi4 __attribute__((ext_vector_type(4)));

__device__ __forceinline__ float term(float x, int t) {
    float d = x - (float)t;
    float w = (x > LOWER_F && x < UPPER_F && t != LABEL_I) ? PENALTY_F : 1.0f;
    return w * d * d;
}

__device__ __forceinline__ float term4(vf4 xv, vi4 tv) {
    return term(xv.x, tv.x) + term(xv.y, tv.y) + term(xv.z, tv.z) + term(xv.w, tv.w);
}

// Tile = 256 threads * 4 chunks = 1024 vf4 from each array (16 KB + 16 KB).
#define TPB 1024

__global__ __launch_bounds__(256, 6) void penal_mse_stage1(
        const vf4* __restrict__ x4,
        const vi4* __restrict__ t4,
        float* __restrict__ partials,
        int n4, int tiles, int n_tail_start, int n_total,
        const float* __restrict__ x_scalar,
        const int*  __restrict__ t_scalar) {
    float s0 = 0.0f, s1 = 0.0f, s2 = 0.0f, s3 = 0.0f;

    for (int tile = blockIdx.x; tile < tiles; tile += gridDim.x) {
        int base = tile * TPB + threadIdx.x;
        const vf4* xp = x4 + base;
        const vi4* tp = t4 + base;
        // 8 independent nontemporal 16 B loads, interleaved x/t so the
        // compiler can consume pair k at vmcnt(6-2k) instead of vmcnt(0).
        vf4 a0 = __builtin_nontemporal_load(xp);
        vi4 b0 = __builtin_nontemporal_load(tp);
        vf4 a1 = __builtin_nontemporal_load(xp + 256);
        vi4 b1 = __builtin_nontemporal_load(tp + 256);
        vf4 a2 = __builtin_nontemporal_load(xp + 512);
        vi4 b2 = __builtin_nontemporal_load(tp + 512);
        vf4 a3 = __builtin_nontemporal_load(xp + 768);
        vi4 b3 = __builtin_nontemporal_load(tp + 768);
        // Pin ALL 8 results to live VGPRs here: register allocation cannot
        // re-serialize the loads (R2/R3 failure mode).
        asm volatile("" : "+v"(a0), "+v"(b0), "+v"(a1), "+v"(b1),
                          "+v"(a2), "+v"(b2), "+v"(a3), "+v"(b3));
        s0 += term4(a0, b0);
        s1 += term4(a1, b1);
        s2 += term4(a2, b2);
        s3 += term4(a3, b3);
    }

    float sum = (s0 + s1) + (s2 + s3);

    // Leftover vf4 groups beyond full tiles (empty for N = 2^25).
    for (int i = tiles * TPB + blockIdx.x * blockDim.x + threadIdx.x;
         i < n4; i += gridDim.x * blockDim.x)
        sum += term4(x4[i], t4[i]);

    // Scalar tail (N % 4 != 0) — empty for N = 2^25.
    for (int j = n_tail_start + blockIdx.x * blockDim.x + threadIdx.x;
         j < n_total; j += gridDim.x * blockDim.x)
        sum += term(x_scalar[j], t_scalar[j]);

    // Wave-64 shuffle reduction, then per-block partial to workspace.
    #pragma unroll
    for (int off = 32; off > 0; off >>= 1)
        sum += __shfl_down(sum, off, 64);

    __shared__ float wsum[4];
    int lane = threadIdx.x & 63;
    int wave = threadIdx.x >> 6;
    if (lane == 0) wsum[wave] = sum;
    __syncthreads();

    if (threadIdx.x == 0)
        partials[blockIdx.x] = (wsum[0] + wsum[1]) + (wsum[2] + wsum[3]);
}

__global__ __launch_bounds__(256) void penal_mse_stage2(
        const float* __restrict__ partials, int nparts,
        float* __restrict__ out, float inv_n) {
    float sum = 0.0f;
    for (int i = threadIdx.x; i < nparts; i += 256)
        sum += partials[i];

    #pragma unroll
    for (int off = 32; off > 0; off >>= 1)
        sum += __shfl_down(sum, off, 64);

    __shared__ float wsum[4];
    int lane = threadIdx.x & 63;
    int wave = threadIdx.x >> 6;
    if (lane == 0) wsum[wave] = sum;
    __syncthreads();

    if (threadIdx.x == 0)
        out[0] = ((wsum[0] + wsum[1]) + (wsum[2] + wsum[3])) * inv_n;
}

extern "C" void kernel_launch(void* const* d_in, const int* in_sizes, int n_in,
                              void* d_out, int out_size, void* d_ws, size_t ws_size,
                              hipStream_t stream) {
    const float* x = (const float*)d_in[0];
    const int*   t = (const int*)d_in[1];
    float* out = (float*)d_out;
    float* partials = (float*)d_ws;

    int n  = in_sizes[0];
    int n4 = n >> 2;              // vf4 groups
    int n_tail_start = n4 << 2;
    int tiles = n4 / TPB;         // full tiles
    float inv_n = 1.0f / (float)n;

    const int block = 256;
    const int grid = 2048;        // 8 blocks/CU; 4 tiles per block at N = 2^25

    penal_mse_stage1<<<grid, block, 0, stream>>>(
        (const vf4*)x, (const vi4*)t, partials,
        n4, tiles, n_tail_start, n, x, t);

    penal_mse_stage2<<<1, block, 0, stream>>>(partials, grid, out, inv_n);
}